// Round 1
// baseline (978.805 us; speedup 1.0000x reference)
//
#include <hip/hip_runtime.h>
#include <hip/hip_bf16.h>

// Problem constants
// N=32, C_IN=C_OUT=64, T=512, V=25, S=3, R=32
// ws float-offset layout
#define XM_OFF   0           // 32*64*25 = 51200 floats
#define ATT_OFF  51200       // 32*3*64*625 = 3840000 floats
#define SSUM_OFF 3891200     // 64
#define SSQ_OFF  3891264     // 64
#define SCL_OFF  3891328     // 64
#define SHF_OFF  3891392     // 64
#define Y_BYTE_OFF (3891456ull * 4ull)   // bf16 y: 26214400 elems = 52.4 MB

// ---------------------------------------------------------------------------
// K1: xm[n,c,v] = mean_t x[n,c,t,v]; block per (n,c). Also zero BN stat accums.
__global__ __launch_bounds__(256) void k_xm(const float* __restrict__ x,
                                            float* __restrict__ ws) {
  const int b = blockIdx.x;            // n*64 + c
  const int tid = threadIdx.x;
  if (b == 0 && tid < 128) ws[SSUM_OFF + tid] = 0.f;   // zero ssum+ssq
  const float* base = x + (size_t)b * 12800;
  float acc[25];
#pragma unroll
  for (int v = 0; v < 25; ++v) acc[v] = 0.f;
  for (int t = tid; t < 512; t += 256) {
    const float* row = base + t * 25;
#pragma unroll
    for (int v = 0; v < 25; ++v) acc[v] += row[v];
  }
  __shared__ float red[256][25];
#pragma unroll
  for (int v = 0; v < 25; ++v) red[tid][v] = acc[v];
  __syncthreads();
  for (int st = 128; st > 0; st >>= 1) {
    if (tid < st) {
#pragma unroll
      for (int v = 0; v < 25; ++v) red[tid][v] += red[tid + st][v];
    }
    __syncthreads();
  }
  if (tid < 25) ws[XM_OFF + b * 25 + tid] = red[0][tid] * (1.0f / 512.0f);
}

// ---------------------------------------------------------------------------
// K2: att[n,s,o,u,v] = (sum_r w4[s,o,r]*relu(q[r,u]-k[r,v]) + b4[s,o])*alpha[s] + A[s,u,v]
// grid 768: (n, s, o-group of 8). q/k recomputed per block (cheap).
__global__ __launch_bounds__(256) void k_att(const float* __restrict__ ws,
    const float* __restrict__ A, const float* __restrict__ w1, const float* __restrict__ b1,
    const float* __restrict__ w2, const float* __restrict__ b2, const float* __restrict__ w4,
    const float* __restrict__ b4, const float* __restrict__ alpha, float* __restrict__ attg) {
  const int b = blockIdx.x;
  const int n = b / 24; const int r = b % 24; const int s = r >> 3; const int og = r & 7;
  const int tid = threadIdx.x;
  __shared__ float xs[1600];   // xm[n][c][v]
  __shared__ float qb[800];    // q[r][v]
  __shared__ float kb[800];    // k[r][v]
  for (int j = tid; j < 1600; j += 256) xs[j] = ws[XM_OFF + n * 1600 + j];
  __syncthreads();
  for (int i = tid; i < 1600; i += 256) {
    const int half = i / 800;          // 0 -> q, 1 -> k
    const int ii = i % 800;
    const int rr = ii / 25, v = ii % 25;
    const float* w = half ? w2 : w1;
    const float* bb = half ? b2 : b1;
    float acc = bb[s * 32 + rr];
    const float* wr = w + (s * 32 + rr) * 64;
#pragma unroll 8
    for (int c = 0; c < 64; ++c) acc += wr[c] * xs[c * 25 + v];
    (half ? kb : qb)[ii] = acc;
  }
  __syncthreads();
  const float al = alpha[s];
  for (int i = tid; i < 5000; i += 256) {
    const int o2 = i / 625, r2 = i % 625;
    const int u = r2 / 25, v = r2 % 25;
    const int o = og * 8 + o2;
    const float* wr = w4 + (s * 64 + o) * 32;
    float acc = 0.f;
#pragma unroll 8
    for (int rr2 = 0; rr2 < 32; ++rr2) {
      const float d = qb[rr2 * 25 + u] - kb[rr2 * 25 + v];
      acc += wr[rr2] * fmaxf(d, 0.f);
    }
    attg[((size_t)(n * 3 + s) * 64 + o) * 625 + r2] =
        (acc + b4[s * 64 + o]) * al + A[s * 625 + r2];
  }
}

// ---------------------------------------------------------------------------
// K3: main fused conv3 + attention aggregation. Block = (n, 16-wide t tile).
// y[n,o,t,u] = sum_s sum_v att[n,s,o,u,v] * (sum_c w3[s,o,c] x[n,c,t,v] + b3[s,o])
// Writes y (bf16) + per-channel partial BN stats.
__global__ __launch_bounds__(256) void k_main(const float* __restrict__ x,
    const float* __restrict__ attg, const float* __restrict__ w3, const float* __restrict__ b3,
    float* __restrict__ ssum, float* __restrict__ ssq, __hip_bfloat16* __restrict__ yg) {
  __shared__ float xt[64 * 400];      // x[c][t*25+v], 102.4 KB
  __shared__ float vt[8 * 400];       // conv3 values for 8 o's
  __shared__ float atts[8 * 650];     // att rows padded to 26
  __shared__ float sS[64], sQ[64];
  const int tid = threadIdx.x;
  const int n = blockIdx.x >> 5, tile = blockIdx.x & 31;
  const int t0 = tile * 16;
  if (tid < 64) { sS[tid] = 0.f; sQ[tid] = 0.f; }
  {
    const float* xb = x + (size_t)n * 819200 + t0 * 25;
    float4* xt4 = (float4*)xt;
    for (int j = tid; j < 6400; j += 256) {
      const int c = j / 100, r = j % 100;
      xt4[c * 100 + r] = *(const float4*)(xb + (size_t)c * 12800 + (r << 2));
    }
  }
  __syncthreads();

  // aggregation unit: 8 o' x 4 t-tiles x 7 u-tiles = 224 units, 4x4 register tile
  const int unit = tid;
  const bool aggact = unit < 224;
  const int oo = unit / 28;
  const int remu = unit % 28;
  const int ta = (remu / 7) * 4;
  const int ua = (remu % 7) * 4;
  const int nu = (ua == 24) ? 1 : 4;
  int arow[4];
#pragma unroll
  for (int k = 0; k < 4; ++k) {
    int uu = ua + k; if (uu > 24) uu = 24;           // clamp (unused lanes)
    arow[k] = oo * 650 + uu * 26;
  }
  const int i0 = tid, i1 = tid + 256;
  const bool has1 = (i1 < 400);

  for (int ob = 0; ob < 8; ++ob) {
    float ya[4][4];
#pragma unroll
    for (int j = 0; j < 4; ++j)
#pragma unroll
      for (int k = 0; k < 4; ++k) ya[j][k] = 0.f;

    for (int s = 0; s < 3; ++s) {
      // (a) prefetch att block into regs (latency hides under conv3)
      float av[20];
      const float* ab = attg + ((size_t)(n * 3 + s) * 64 + ob * 8) * 625;
#pragma unroll
      for (int k = 0; k < 20; ++k) {
        const int j = tid + (k << 8);
        av[k] = (j < 5000) ? ab[j] : 0.f;
      }
      // conv3 into regs: items i0 (and i1), 8 o's blocked -> 1 LDS read per 8 FMA
      const float* w3b = w3 + ((size_t)s * 64 + ob * 8) * 64;
      const float* b3b = b3 + s * 64 + ob * 8;
      float a0[8], a1[8];
#pragma unroll
      for (int o2 = 0; o2 < 8; ++o2) { const float bb = b3b[o2]; a0[o2] = bb; a1[o2] = bb; }
      for (int c = 0; c < 64; c += 4) {
#pragma unroll
        for (int cc = 0; cc < 4; ++cc) {
          const float x0 = xt[(c + cc) * 400 + i0];
          const float x1 = has1 ? xt[(c + cc) * 400 + i1] : 0.f;
#pragma unroll
          for (int o2 = 0; o2 < 8; ++o2) {
            const float w = w3b[o2 * 64 + c + cc];   // wave-uniform -> s_load
            a0[o2] = fmaf(w, x0, a0[o2]);
            a1[o2] = fmaf(w, x1, a1[o2]);
          }
        }
      }
      __syncthreads();   // (b) previous agg done; vt/atts free
      // (c) publish vt + atts
#pragma unroll
      for (int o2 = 0; o2 < 8; ++o2) {
        vt[o2 * 400 + i0] = a0[o2];
        if (has1) vt[o2 * 400 + i1] = a1[o2];
      }
#pragma unroll
      for (int k = 0; k < 20; ++k) {
        const int j = tid + (k << 8);
        if (j < 5000) {
          const int o2 = j / 625, r2 = j % 625;
          const int u = r2 / 25, v = r2 % 25;
          atts[o2 * 650 + u * 26 + v] = av[k];
        }
      }
      __syncthreads();   // (d)
      // (e) aggregation: ya[j][k] += vt[oo][ta+j][v] * att[oo][ua+k][v]
      if (aggact) {
        const int vbase = oo * 400 + ta * 25;
#pragma unroll
        for (int v = 0; v < 25; ++v) {
          float av4[4], vv4[4];
#pragma unroll
          for (int k = 0; k < 4; ++k) av4[k] = atts[arow[k] + v];
#pragma unroll
          for (int j = 0; j < 4; ++j) vv4[j] = vt[vbase + j * 25 + v];
#pragma unroll
          for (int j = 0; j < 4; ++j)
#pragma unroll
            for (int k = 0; k < 4; ++k) ya[j][k] = fmaf(vv4[j], av4[k], ya[j][k]);
        }
      }
    } // s

    if (aggact) {
      float s1 = 0.f, s2 = 0.f;
      const int o = ob * 8 + oo;
      __hip_bfloat16* yb = yg + ((size_t)(n * 64 + o) * 512 + (t0 + ta)) * 25 + ua;
#pragma unroll
      for (int j = 0; j < 4; ++j) {
#pragma unroll
        for (int k = 0; k < 4; ++k) {
          if (k < nu) {
            const float yv = ya[j][k];
            s1 += yv; s2 += yv * yv;
            yb[j * 25 + k] = __float2bfloat16(yv);
          }
        }
      }
      atomicAdd(&sS[o], s1);
      atomicAdd(&sQ[o], s2);
    }
  } // ob
  __syncthreads();
  if (tid < 64) {
    atomicAdd(&ssum[tid], sS[tid]);
    atomicAdd(&ssq[tid], sQ[tid]);
  }
}

// ---------------------------------------------------------------------------
// K4: BN train-mode stats -> scale/shift
__global__ __launch_bounds__(64) void k_stats(const float* __restrict__ ssum,
    const float* __restrict__ ssq, const float* __restrict__ gamma,
    const float* __restrict__ beta, float* __restrict__ scl, float* __restrict__ shf) {
  const int o = threadIdx.x;
  const float inv = 1.0f / 409600.0f;          // N*T*V
  const float mu = ssum[o] * inv;
  const float var = ssq[o] * inv - mu * mu;    // biased
  const float rstd = rsqrtf(var + 1e-5f);
  const float sc = gamma[o] * rstd;
  scl[o] = sc;
  shf[o] = beta[o] - mu * sc;
}

// ---------------------------------------------------------------------------
// K5: out = relu(y) + y*scale[o] + shift[o] + x   (float4 / 4x bf16 per thread-iter)
__global__ __launch_bounds__(256) void k_final(const float* __restrict__ x,
    const __hip_bfloat16* __restrict__ yg, const float* __restrict__ scl,
    const float* __restrict__ shf, float* __restrict__ out) {
  const int stride = gridDim.x * blockDim.x;
  for (int i = blockIdx.x * 256 + threadIdx.x; i < 6553600; i += stride) {
    const int o = (i / 3200) & 63;             // 3200 float4 per (n,o) slab
    const float sc = scl[o], sh = shf[o];
    const float4 xv = ((const float4*)x)[i];
    const ushort4 yu = ((const ushort4*)yg)[i];
    const float y0 = __uint_as_float((unsigned)yu.x << 16);
    const float y1 = __uint_as_float((unsigned)yu.y << 16);
    const float y2 = __uint_as_float((unsigned)yu.z << 16);
    const float y3 = __uint_as_float((unsigned)yu.w << 16);
    float4 r;
    r.x = fmaxf(y0, 0.f) + y0 * sc + sh + xv.x;
    r.y = fmaxf(y1, 0.f) + y1 * sc + sh + xv.y;
    r.z = fmaxf(y2, 0.f) + y2 * sc + sh + xv.z;
    r.w = fmaxf(y3, 0.f) + y3 * sc + sh + xv.w;
    ((float4*)out)[i] = r;
  }
}

// ---------------------------------------------------------------------------
extern "C" void kernel_launch(void* const* d_in, const int* in_sizes, int n_in,
                              void* d_out, int out_size, void* d_ws, size_t ws_size,
                              hipStream_t stream) {
  const float* x     = (const float*)d_in[0];
  const float* A     = (const float*)d_in[1];
  const float* w1    = (const float*)d_in[2];
  const float* b1    = (const float*)d_in[3];
  const float* w2    = (const float*)d_in[4];
  const float* b2    = (const float*)d_in[5];
  const float* w3    = (const float*)d_in[6];
  const float* b3    = (const float*)d_in[7];
  const float* w4    = (const float*)d_in[8];
  const float* b4    = (const float*)d_in[9];
  const float* alpha = (const float*)d_in[10];
  const float* gamma = (const float*)d_in[11];
  const float* beta  = (const float*)d_in[12];
  float* ws = (float*)d_ws;
  float* attg = ws + ATT_OFF;
  __hip_bfloat16* yg = (__hip_bfloat16*)((char*)d_ws + Y_BYTE_OFF);
  float* out = (float*)d_out;

  k_xm<<<2048, 256, 0, stream>>>(x, ws);
  k_att<<<768, 256, 0, stream>>>(ws, A, w1, b1, w2, b2, w4, b4, alpha, attg);
  k_main<<<1024, 256, 0, stream>>>(x, attg, w3, b3, ws + SSUM_OFF, ws + SSQ_OFF, yg);
  k_stats<<<1, 64, 0, stream>>>(ws + SSUM_OFF, ws + SSQ_OFF, gamma, beta,
                                ws + SCL_OFF, ws + SHF_OFF);
  k_final<<<2048, 256, 0, stream>>>(x, yg, ws + SCL_OFF, ws + SHF_OFF, out);
}

// Round 2
// 471.877 us; speedup vs baseline: 2.0743x; 2.0743x over previous
//
#include <hip/hip_runtime.h>
#include <hip/hip_bf16.h>

// Problem constants: N=32, C_IN=C_OUT=64, T=512, V=25, S=3, R=32
// ws float-offset layout
#define XM_OFF   0           // 32*64*25 = 51200 floats
#define ATT_OFF  51200       // 32*3*64*625 = 3840000 floats
#define SSUM_OFF 3891200     // 64
#define SSQ_OFF  3891264     // 64
#define SCL_OFF  3891328     // 64
#define SHF_OFF  3891392     // 64
#define Y_BYTE_OFF  (3891456ull * 4ull)            // bf16 y: 26214400 elems = 52.4 MB
#define VT_BYTE_OFF (Y_BYTE_OFF + 52428800ull)     // bf16 vt half-n: 16*3*64*12800 = 39321600 elems

// MFMA fragment layout for 16x16x32 bf16:
//   0: two K-16 halves, each classic k=(l>>4)*4+i   (elems 0..3 = k-half0, 4..7 = k-half1)
//   1: contiguous-8: k=(l>>4)*8+i
#define CONV_SWAP 0

typedef __attribute__((ext_vector_type(8))) short short8;
typedef __attribute__((ext_vector_type(4))) float f32x4;

__device__ __forceinline__ ushort f2bs(float f) {
  __hip_bfloat16 h = __float2bfloat16(f);
  ushort u; __builtin_memcpy(&u, &h, 2); return u;
}
__device__ __forceinline__ float bs2f(ushort u) {
  return __uint_as_float((unsigned)u << 16);
}

// ---------------------------------------------------------------------------
// K1: xm[n,c,v] = mean_t x[n,c,t,v]; block per (n,c). Also zero BN stat accums.
__global__ __launch_bounds__(256) void k_xm(const float* __restrict__ x,
                                            float* __restrict__ ws) {
  const int b = blockIdx.x;            // n*64 + c
  const int tid = threadIdx.x;
  if (b == 0 && tid < 128) ws[SSUM_OFF + tid] = 0.f;   // zero ssum+ssq
  const float* base = x + (size_t)b * 12800;
  float acc[25];
#pragma unroll
  for (int v = 0; v < 25; ++v) acc[v] = 0.f;
  for (int t = tid; t < 512; t += 256) {
    const float* row = base + t * 25;
#pragma unroll
    for (int v = 0; v < 25; ++v) acc[v] += row[v];
  }
  __shared__ float red[256][25];
#pragma unroll
  for (int v = 0; v < 25; ++v) red[tid][v] = acc[v];
  __syncthreads();
  for (int st = 128; st > 0; st >>= 1) {
    if (tid < st) {
#pragma unroll
      for (int v = 0; v < 25; ++v) red[tid][v] += red[tid + st][v];
    }
    __syncthreads();
  }
  if (tid < 25) ws[XM_OFF + b * 25 + tid] = red[0][tid] * (1.0f / 512.0f);
}

// ---------------------------------------------------------------------------
// K2: att[n,s,o,u,v] = (sum_r w4[s,o,r]*relu(q[r,u]-k[r,v]) + b4[s,o])*alpha[s] + A[s,u,v]
__global__ __launch_bounds__(256) void k_att(const float* __restrict__ ws,
    const float* __restrict__ A, const float* __restrict__ w1, const float* __restrict__ b1,
    const float* __restrict__ w2, const float* __restrict__ b2, const float* __restrict__ w4,
    const float* __restrict__ b4, const float* __restrict__ alpha, float* __restrict__ attg) {
  const int b = blockIdx.x;
  const int n = b / 24; const int r = b % 24; const int s = r >> 3; const int og = r & 7;
  const int tid = threadIdx.x;
  __shared__ float xs[1600];   // xm[n][c][v]
  __shared__ float qb[800];    // q[r][v]
  __shared__ float kb[800];    // k[r][v]
  for (int j = tid; j < 1600; j += 256) xs[j] = ws[XM_OFF + n * 1600 + j];
  __syncthreads();
  for (int i = tid; i < 1600; i += 256) {
    const int half = i / 800;
    const int ii = i % 800;
    const int rr = ii / 25, v = ii % 25;
    const float* w = half ? w2 : w1;
    const float* bb = half ? b2 : b1;
    float acc = bb[s * 32 + rr];
    const float* wr = w + (s * 32 + rr) * 64;
#pragma unroll 8
    for (int c = 0; c < 64; ++c) acc += wr[c] * xs[c * 25 + v];
    (half ? kb : qb)[ii] = acc;
  }
  __syncthreads();
  const float al = alpha[s];
  for (int i = tid; i < 5000; i += 256) {
    const int o2 = i / 625, r2 = i % 625;
    const int u = r2 / 25, v = r2 % 25;
    const int o = og * 8 + o2;
    const float* wr = w4 + (s * 64 + o) * 32;
    float acc = 0.f;
#pragma unroll 8
    for (int rr2 = 0; rr2 < 32; ++rr2) {
      const float d = qb[rr2 * 25 + u] - kb[rr2 * 25 + v];
      acc += wr[rr2] * fmaxf(d, 0.f);
    }
    attg[((size_t)(n * 3 + s) * 64 + o) * 625 + r2] =
        (acc + b4[s * 64 + o]) * al + A[s * 625 + r2];
  }
}

// ---------------------------------------------------------------------------
// K3: conv3 via MFMA bf16. Block = (nh, item-chunk of 256). 256 thr = 4 waves.
// vt[nh][s][o][item] = sum_c w3[s,o,c]*x[n,c,item] + b3[s,o]   (bf16, o-major)
__global__ __launch_bounds__(256) void k_conv3(const float* __restrict__ x,
    const float* __restrict__ w3, const float* __restrict__ b3,
    ushort* __restrict__ vt, int n_base) {
  __shared__ ushort xbf[2][16][64][8];   // [kb][ntile][lane][e]  (frag order) 32KB
  __shared__ ushort shv[64 * 256];       // [o][item ^ ((o&7)<<3)] 32KB
  const int tid = threadIdx.x;
  const int nh = blockIdx.x / 50, chunk = blockIdx.x % 50;
  const int n = n_base + nh;
  const int item0 = chunk * 256;

  // ---- stage x -> frag-order bf16 LDS. thread owns item = tid.
  {
    const float* xb = x + (size_t)n * 819200 + item0 + tid;
    const int col = tid & 15, nt = tid >> 4;
#pragma unroll
    for (int cq = 0; cq < 16; ++cq) {
      const int c0 = cq * 4;
      const float f0 = xb[(size_t)(c0 + 0) * 12800];
      const float f1 = xb[(size_t)(c0 + 1) * 12800];
      const float f2 = xb[(size_t)(c0 + 2) * 12800];
      const float f3 = xb[(size_t)(c0 + 3) * 12800];
      ushort4 p;
      p.x = f2bs(f0); p.y = f2bs(f1); p.z = f2bs(f2); p.w = f2bs(f3);
      const int kb = c0 >> 5;
#if CONV_SWAP == 0
      const int h  = (c0 >> 4) & 1;
      const int kg = (c0 >> 2) & 3;
      *(ushort4*)&xbf[kb][nt][kg * 16 + col][h * 4] = p;
#else
      const int cp = c0 & 31;
      *(ushort4*)&xbf[kb][nt][(cp >> 3) * 16 + col][c0 & 4] = p;
#endif
    }
  }
  __syncthreads();

  const int lane = tid & 63, wid = tid >> 6;
  const int o0 = wid * 16;               // wave's M-tile
  const int orow = o0 + (lane & 15);
  const int kg = lane >> 4;

  // ---- preload A-frags (w3) + b3
  short8 afr[3][2];
  float4 b3v[3];
#pragma unroll
  for (int s = 0; s < 3; ++s) {
    const float* wrow = w3 + ((size_t)s * 64 + orow) * 64;
#pragma unroll
    for (int kb2 = 0; kb2 < 2; ++kb2) {
#if CONV_SWAP == 0
      const float4 lo = *(const float4*)(wrow + kb2 * 32 + kg * 4);
      const float4 hi = *(const float4*)(wrow + kb2 * 32 + 16 + kg * 4);
#else
      const float4 lo = *(const float4*)(wrow + kb2 * 32 + kg * 8);
      const float4 hi = *(const float4*)(wrow + kb2 * 32 + kg * 8 + 4);
#endif
      short8 a;
      a[0] = (short)f2bs(lo.x); a[1] = (short)f2bs(lo.y);
      a[2] = (short)f2bs(lo.z); a[3] = (short)f2bs(lo.w);
      a[4] = (short)f2bs(hi.x); a[5] = (short)f2bs(hi.y);
      a[6] = (short)f2bs(hi.z); a[7] = (short)f2bs(hi.w);
      afr[s][kb2] = a;
    }
    b3v[s] = *(const float4*)(b3 + s * 64 + o0 + (lane >> 4) * 4);
  }

  const int obase = o0 + (lane >> 4) * 4;
  const int colit = lane & 15;

  for (int s = 0; s < 3; ++s) {
#pragma unroll
    for (int nt = 0; nt < 16; ++nt) {
      f32x4 acc;
      acc[0] = b3v[s].x; acc[1] = b3v[s].y; acc[2] = b3v[s].z; acc[3] = b3v[s].w;
      const short8 bf0 = *(const short8*)&xbf[0][nt][lane][0];
      const short8 bf1 = *(const short8*)&xbf[1][nt][lane][0];
      acc = __builtin_amdgcn_mfma_f32_16x16x32_bf16(afr[s][0], bf0, acc, 0, 0, 0);
      acc = __builtin_amdgcn_mfma_f32_16x16x32_bf16(afr[s][1], bf1, acc, 0, 0, 0);
      const int item = nt * 16 + colit;
#pragma unroll
      for (int r = 0; r < 4; ++r) {
        const int oo = obase + r;
        shv[oo * 256 + (item ^ ((oo & 7) << 3))] = f2bs(acc[r]);
      }
    }
    __syncthreads();
    // ---- coalesced readout: thread -> (o = tid>>2, seg = tid&3)
    {
      const int o = tid >> 2, seg = tid & 3;
      ushort* dst = vt + (((size_t)nh * 3 + s) * 64 + o) * 12800 + item0;
      const ushort* srow = &shv[o * 256];
      const int xr = (o & 7) << 3;
#pragma unroll
      for (int g = 0; g < 8; ++g) {
        const int ib = g * 32 + seg * 8;
        *(int4*)(dst + ib) = *(const int4*)(srow + (ib ^ xr));
      }
    }
    __syncthreads();
  }
}

// ---------------------------------------------------------------------------
// K4: aggregation. Block=(nh,o,tchunk), thread=t. att via SGPR (uniform), vt row in regs.
// y[n,o,t,u] = sum_s sum_v att[n,s,o,u,v] * vt[nh,s,o,t,v]
__global__ __launch_bounds__(256) void k_agg(const ushort* __restrict__ vt,
    const float* __restrict__ attg, float* __restrict__ ssum, float* __restrict__ ssq,
    ushort* __restrict__ yg, int n_base) {
  const int bid = blockIdx.x;
  const int tc = bid & 1, o = (bid >> 1) & 63, nh = bid >> 7;
  const int n = n_base + nh;
  const int t = tc * 256 + threadIdx.x;
  const float* ab = attg + ((size_t)(n * 3) * 64 + o) * 625;
  float acc[25];
#pragma unroll
  for (int u = 0; u < 25; ++u) acc[u] = 0.f;

  for (int s = 0; s < 3; ++s) {
    const ushort* vr = vt + ((((size_t)nh * 3 + s) * 64 + o) * 512 + t) * 25;
    float xv[25];
#pragma unroll
    for (int v = 0; v < 25; ++v) xv[v] = bs2f(vr[v]);
    const float* ar = ab + s * 40000;   // s*64*625
#pragma unroll
    for (int u = 0; u < 25; ++u) {
      const float* arr = ar + u * 25;
#pragma unroll
      for (int v = 0; v < 25; ++v) acc[u] = fmaf(arr[v], xv[v], acc[u]);
    }
  }

  ushort* yr = yg + (((size_t)n * 64 + o) * 512 + t) * 25;
  float s1 = 0.f, s2 = 0.f;
#pragma unroll
  for (int u = 0; u < 25; ++u) {
    const float yv = acc[u];
    s1 += yv; s2 += yv * yv;
    yr[u] = f2bs(yv);
  }
  // reduce stats (all threads share o)
#pragma unroll
  for (int off = 32; off > 0; off >>= 1) {
    s1 += __shfl_down(s1, off);
    s2 += __shfl_down(s2, off);
  }
  __shared__ float rs[8];
  const int lane = threadIdx.x & 63, wid = threadIdx.x >> 6;
  if (lane == 0) { rs[wid] = s1; rs[4 + wid] = s2; }
  __syncthreads();
  if (threadIdx.x == 0) {
    atomicAdd(&ssum[o], rs[0] + rs[1] + rs[2] + rs[3]);
    atomicAdd(&ssq[o], rs[4] + rs[5] + rs[6] + rs[7]);
  }
}

// ---------------------------------------------------------------------------
// K5: BN train-mode stats -> scale/shift
__global__ __launch_bounds__(64) void k_stats(const float* __restrict__ ssum,
    const float* __restrict__ ssq, const float* __restrict__ gamma,
    const float* __restrict__ beta, float* __restrict__ scl, float* __restrict__ shf) {
  const int o = threadIdx.x;
  const float inv = 1.0f / 409600.0f;          // N*T*V
  const float mu = ssum[o] * inv;
  const float var = ssq[o] * inv - mu * mu;    // biased
  const float rstd = rsqrtf(var + 1e-5f);
  const float sc = gamma[o] * rstd;
  scl[o] = sc;
  shf[o] = beta[o] - mu * sc;
}

// ---------------------------------------------------------------------------
// K6: out = relu(y) + y*scale[o] + shift[o] + x
__global__ __launch_bounds__(256) void k_final(const float* __restrict__ x,
    const ushort* __restrict__ yg, const float* __restrict__ scl,
    const float* __restrict__ shf, float* __restrict__ out) {
  const int stride = gridDim.x * blockDim.x;
  for (int i = blockIdx.x * 256 + threadIdx.x; i < 6553600; i += stride) {
    const int o = (i / 3200) & 63;             // 3200 float4 per (n,o) slab
    const float sc = scl[o], sh = shf[o];
    const float4 xv = ((const float4*)x)[i];
    const ushort4 yu = ((const ushort4*)yg)[i];
    const float y0 = bs2f(yu.x), y1 = bs2f(yu.y), y2 = bs2f(yu.z), y3 = bs2f(yu.w);
    float4 r;
    r.x = fmaxf(y0, 0.f) + y0 * sc + sh + xv.x;
    r.y = fmaxf(y1, 0.f) + y1 * sc + sh + xv.y;
    r.z = fmaxf(y2, 0.f) + y2 * sc + sh + xv.z;
    r.w = fmaxf(y3, 0.f) + y3 * sc + sh + xv.w;
    ((float4*)out)[i] = r;
  }
}

// ---------------------------------------------------------------------------
extern "C" void kernel_launch(void* const* d_in, const int* in_sizes, int n_in,
                              void* d_out, int out_size, void* d_ws, size_t ws_size,
                              hipStream_t stream) {
  const float* x     = (const float*)d_in[0];
  const float* A     = (const float*)d_in[1];
  const float* w1    = (const float*)d_in[2];
  const float* b1    = (const float*)d_in[3];
  const float* w2    = (const float*)d_in[4];
  const float* b2    = (const float*)d_in[5];
  const float* w3    = (const float*)d_in[6];
  const float* b3    = (const float*)d_in[7];
  const float* w4    = (const float*)d_in[8];
  const float* b4    = (const float*)d_in[9];
  const float* alpha = (const float*)d_in[10];
  const float* gamma = (const float*)d_in[11];
  const float* beta  = (const float*)d_in[12];
  float* ws = (float*)d_ws;
  float* attg = ws + ATT_OFF;
  ushort* yg = (ushort*)((char*)d_ws + Y_BYTE_OFF);
  ushort* vtb = (ushort*)((char*)d_ws + VT_BYTE_OFF);
  float* out = (float*)d_out;

  k_xm<<<2048, 256, 0, stream>>>(x, ws);
  k_att<<<768, 256, 0, stream>>>(ws, A, w1, b1, w2, b2, w4, b4, alpha, attg);
  for (int ph = 0; ph < 2; ++ph) {
    const int n_base = ph * 16;
    k_conv3<<<800, 256, 0, stream>>>(x, w3, b3, vtb, n_base);
    k_agg<<<2048, 256, 0, stream>>>(vtb, attg, ws + SSUM_OFF, ws + SSQ_OFF, yg, n_base);
  }
  k_stats<<<1, 64, 0, stream>>>(ws + SSUM_OFF, ws + SSQ_OFF, gamma, beta,
                                ws + SCL_OFF, ws + SHF_OFF);
  k_final<<<2048, 256, 0, stream>>>(x, yg, ws + SCL_OFF, ws + SHF_OFF, out);
}

// Round 3
// 419.486 us; speedup vs baseline: 2.3333x; 1.1249x over previous
//
#include <hip/hip_runtime.h>
#include <hip/hip_bf16.h>

// Problem constants: N=32, C_IN=C_OUT=64, T=512, V=25, S=3, R=32
// ws float-offset layout
#define XM_OFF   0           // 32*64*25 = 51200 floats
#define ATT_OFF  51200       // 32*3*64*625 = 3840000 floats
#define SSUM_OFF 3891200     // 64
#define SSQ_OFF  3891264     // 64
#define SCL_OFF  3891328     // 64
#define SHF_OFF  3891392     // 64
#define Y_BYTE_OFF  (3891456ull * 4ull)            // bf16 y: 26214400 elems = 52.4 MB
#define VT_BYTE_OFF (Y_BYTE_OFF + 52428800ull)     // bf16 vt half-n: 16*3*64*12800 elems

typedef __attribute__((ext_vector_type(8))) short short8;
typedef __attribute__((ext_vector_type(4))) float f32x4;

__device__ __forceinline__ ushort f2bs(float f) {
  __hip_bfloat16 h = __float2bfloat16(f);
  ushort u; __builtin_memcpy(&u, &h, 2); return u;
}
__device__ __forceinline__ float bs2f(ushort u) {
  return __uint_as_float((unsigned)u << 16);
}

// ---------------------------------------------------------------------------
// K1: xm[n,c,v] = mean_t x[n,c,t,v]; block per (n,c). Also zero BN stat accums.
__global__ __launch_bounds__(256) void k_xm(const float* __restrict__ x,
                                            float* __restrict__ ws) {
  const int b = blockIdx.x;            // n*64 + c
  const int tid = threadIdx.x;
  if (b == 0 && tid < 128) ws[SSUM_OFF + tid] = 0.f;   // zero ssum+ssq
  const float* base = x + (size_t)b * 12800;
  float acc[25];
#pragma unroll
  for (int v = 0; v < 25; ++v) acc[v] = 0.f;
  for (int t = tid; t < 512; t += 256) {
    const float* row = base + t * 25;
#pragma unroll
    for (int v = 0; v < 25; ++v) acc[v] += row[v];
  }
  __shared__ float red[256][25];
#pragma unroll
  for (int v = 0; v < 25; ++v) red[tid][v] = acc[v];
  __syncthreads();
  for (int st = 128; st > 0; st >>= 1) {
    if (tid < st) {
#pragma unroll
      for (int v = 0; v < 25; ++v) red[tid][v] += red[tid + st][v];
    }
    __syncthreads();
  }
  if (tid < 25) ws[XM_OFF + b * 25 + tid] = red[0][tid] * (1.0f / 512.0f);
}

// ---------------------------------------------------------------------------
// K2: att[n,s,o,u,v] = (sum_r w4[s,o,r]*relu(q[r,u]-k[r,v]) + b4[s,o])*alpha[s] + A[s,u,v]
__global__ __launch_bounds__(256) void k_att(const float* __restrict__ ws,
    const float* __restrict__ A, const float* __restrict__ w1, const float* __restrict__ b1,
    const float* __restrict__ w2, const float* __restrict__ b2, const float* __restrict__ w4,
    const float* __restrict__ b4, const float* __restrict__ alpha, float* __restrict__ attg) {
  const int b = blockIdx.x;
  const int n = b / 24; const int r = b % 24; const int s = r >> 3; const int og = r & 7;
  const int tid = threadIdx.x;
  __shared__ float xs[1600];   // xm[n][c][v]
  __shared__ float qb[800];    // q[r][v]
  __shared__ float kb[800];    // k[r][v]
  for (int j = tid; j < 1600; j += 256) xs[j] = ws[XM_OFF + n * 1600 + j];
  __syncthreads();
  for (int i = tid; i < 1600; i += 256) {
    const int half = i / 800;
    const int ii = i % 800;
    const int rr = ii / 25, v = ii % 25;
    const float* w = half ? w2 : w1;
    const float* bb = half ? b2 : b1;
    float acc = bb[s * 32 + rr];
    const float* wr = w + (s * 32 + rr) * 64;
#pragma unroll 8
    for (int c = 0; c < 64; ++c) acc += wr[c] * xs[c * 25 + v];
    (half ? kb : qb)[ii] = acc;
  }
  __syncthreads();
  const float al = alpha[s];
  for (int i = tid; i < 5000; i += 256) {
    const int o2 = i / 625, r2 = i % 625;
    const int u = r2 / 25, v = r2 % 25;
    const int o = og * 8 + o2;
    const float* wr = w4 + (s * 64 + o) * 32;
    float acc = 0.f;
#pragma unroll 8
    for (int rr2 = 0; rr2 < 32; ++rr2) {
      const float d = qb[rr2 * 25 + u] - kb[rr2 * 25 + v];
      acc += wr[rr2] * fmaxf(d, 0.f);
    }
    attg[((size_t)(n * 3 + s) * 64 + o) * 625 + r2] =
        (acc + b4[s * 64 + o]) * al + A[s * 625 + r2];
  }
}

// ---------------------------------------------------------------------------
// K3: conv3 via MFMA bf16. Block = (nh, item-chunk of 256). 256 thr = 4 waves.
// vt[nh][s][o][item] = sum_c w3[s,o,c]*x[n,c,item] + b3[s,o]   (bf16, o-major)
__global__ __launch_bounds__(256) void k_conv3(const float* __restrict__ x,
    const float* __restrict__ w3, const float* __restrict__ b3,
    ushort* __restrict__ vt, int n_base) {
  __shared__ ushort xbf[2][16][64][8];   // [kb][ntile][lane][e]  (frag order) 32KB
  __shared__ ushort shv[64 * 256];       // [o][item ^ ((o&7)<<3)] 32KB
  const int tid = threadIdx.x;
  const int nh = blockIdx.x / 50, chunk = blockIdx.x % 50;
  const int n = n_base + nh;
  const int item0 = chunk * 256;

  // ---- stage x -> frag-order bf16 LDS. thread owns item = tid.
  {
    const float* xb = x + (size_t)n * 819200 + item0 + tid;
    const int col = tid & 15, nt = tid >> 4;
#pragma unroll
    for (int cq = 0; cq < 16; ++cq) {
      const int c0 = cq * 4;
      const float f0 = xb[(size_t)(c0 + 0) * 12800];
      const float f1 = xb[(size_t)(c0 + 1) * 12800];
      const float f2 = xb[(size_t)(c0 + 2) * 12800];
      const float f3 = xb[(size_t)(c0 + 3) * 12800];
      ushort4 p;
      p.x = f2bs(f0); p.y = f2bs(f1); p.z = f2bs(f2); p.w = f2bs(f3);
      const int kb = c0 >> 5;
      const int h  = (c0 >> 4) & 1;
      const int kg = (c0 >> 2) & 3;
      *(ushort4*)&xbf[kb][nt][kg * 16 + col][h * 4] = p;
    }
  }
  __syncthreads();

  const int lane = tid & 63, wid = tid >> 6;
  const int o0 = wid * 16;               // wave's M-tile
  const int orow = o0 + (lane & 15);
  const int kg = lane >> 4;

  // ---- preload A-frags (w3) + b3
  short8 afr[3][2];
  float4 b3v[3];
#pragma unroll
  for (int s = 0; s < 3; ++s) {
    const float* wrow = w3 + ((size_t)s * 64 + orow) * 64;
#pragma unroll
    for (int kb2 = 0; kb2 < 2; ++kb2) {
      const float4 lo = *(const float4*)(wrow + kb2 * 32 + kg * 4);
      const float4 hi = *(const float4*)(wrow + kb2 * 32 + 16 + kg * 4);
      short8 a;
      a[0] = (short)f2bs(lo.x); a[1] = (short)f2bs(lo.y);
      a[2] = (short)f2bs(lo.z); a[3] = (short)f2bs(lo.w);
      a[4] = (short)f2bs(hi.x); a[5] = (short)f2bs(hi.y);
      a[6] = (short)f2bs(hi.z); a[7] = (short)f2bs(hi.w);
      afr[s][kb2] = a;
    }
    b3v[s] = *(const float4*)(b3 + s * 64 + o0 + (lane >> 4) * 4);
  }

  const int obase = o0 + (lane >> 4) * 4;
  const int colit = lane & 15;

  for (int s = 0; s < 3; ++s) {
#pragma unroll
    for (int nt = 0; nt < 16; ++nt) {
      f32x4 acc;
      acc[0] = b3v[s].x; acc[1] = b3v[s].y; acc[2] = b3v[s].z; acc[3] = b3v[s].w;
      const short8 bf0 = *(const short8*)&xbf[0][nt][lane][0];
      const short8 bf1 = *(const short8*)&xbf[1][nt][lane][0];
      acc = __builtin_amdgcn_mfma_f32_16x16x32_bf16(afr[s][0], bf0, acc, 0, 0, 0);
      acc = __builtin_amdgcn_mfma_f32_16x16x32_bf16(afr[s][1], bf1, acc, 0, 0, 0);
      const int item = nt * 16 + colit;
#pragma unroll
      for (int r = 0; r < 4; ++r) {
        const int oo = obase + r;
        shv[oo * 256 + (item ^ ((oo & 7) << 3))] = f2bs(acc[r]);
      }
    }
    __syncthreads();
    // ---- coalesced readout: thread -> (o = tid>>2, seg = tid&3)
    {
      const int o = tid >> 2, seg = tid & 3;
      ushort* dst = vt + (((size_t)nh * 3 + s) * 64 + o) * 12800 + item0;
      const ushort* srow = &shv[o * 256];
      const int xr = (o & 7) << 3;
#pragma unroll
      for (int g = 0; g < 8; ++g) {
        const int ib = g * 32 + seg * 8;
        *(int4*)(dst + ib) = *(const int4*)(srow + (ib ^ xr));
      }
    }
    __syncthreads();
  }
}

// ---------------------------------------------------------------------------
// K4: aggregation via MFMA. Block=(nh,o), 256 thr = 4 waves, wave w -> t in [w*128,(w+1)*128).
// y[n,o,t,u] = sum_s sum_v att[n,s,o,u,v] * vt[nh,s,o,t,v]
// GEMM per (n,o): A=att (M=u 25->2x16), B=vt (N=t 512), K=v (25->32 zero-pad), 3 K-steps (s).
__global__ __launch_bounds__(256) void k_agg(const ushort* __restrict__ vt,
    const float* __restrict__ attg, float* __restrict__ ssum, float* __restrict__ ssq,
    ushort* __restrict__ yg, int n_base) {
  __shared__ __align__(16) ushort vs[14336];   // staging 12800 / y-pack 512*28
  const int bid = blockIdx.x;
  const int o = bid & 63, nh = bid >> 6;
  const int n = n_base + nh;
  const int tid = threadIdx.x;
  const int lane = tid & 63, wid = tid >> 6;
  const int kg = lane >> 4;
  const int trow = lane & 15;

  // ---- A-frags from att (L2-hot): afr[s][mt]; u = mt*16+(l&15), k=v mapping as conv3
  short8 afr[3][2];
#pragma unroll
  for (int s = 0; s < 3; ++s) {
    const float* ab = attg + ((size_t)(n * 3 + s) * 64 + o) * 625;
#pragma unroll
    for (int mt = 0; mt < 2; ++mt) {
      const int u = mt * 16 + (lane & 15);
      short8 a;
#pragma unroll
      for (int i = 0; i < 8; ++i) {
        const int v = kg * 4 + (i & 3) + ((i >> 2) << 4);
        float val = (u < 25 && v < 25) ? ab[u * 25 + v] : 0.f;
        a[i] = (short)f2bs(val);
      }
      afr[s][mt] = a;
    }
  }

  f32x4 acc0[8], acc1[8];
#pragma unroll
  for (int nt = 0; nt < 8; ++nt) {
    acc0[nt] = (f32x4)0.f; acc1[nt] = (f32x4)0.f;
  }

  for (int s = 0; s < 3; ++s) {
    // stage vt s-slab (contiguous 25.6KB) into LDS
    const ushort* vslab = vt + (((size_t)nh * 3 + s) * 64 + o) * 12800;
    for (int j = tid; j < 1600; j += 256)
      *(int4*)&vs[j * 8] = *(const int4*)&vslab[j * 8];
    __syncthreads();
#pragma unroll
    for (int nt = 0; nt < 8; ++nt) {
      const int t = wid * 128 + nt * 16 + trow;
      short8 b;
#pragma unroll
      for (int i = 0; i < 8; ++i) {
        const int v = kg * 4 + (i & 3) + ((i >> 2) << 4);
        b[i] = (v < 25) ? (short)vs[t * 25 + v] : (short)0;
      }
      acc0[nt] = __builtin_amdgcn_mfma_f32_16x16x32_bf16(afr[s][0], b, acc0[nt], 0, 0, 0);
      acc1[nt] = __builtin_amdgcn_mfma_f32_16x16x32_bf16(afr[s][1], b, acc1[nt], 0, 0, 0);
    }
    __syncthreads();   // frags consumed; vs free for next s
  }

  // ---- epilogue: pack y (bf16) via LDS [512][28], then coalesced stores + BN stats
  // C/D: t = t0 + (lane&15), u = mt*16 + (lane>>4)*4 + r
#pragma unroll
  for (int nt = 0; nt < 8; ++nt) {
    const int t = wid * 128 + nt * 16 + trow;
#pragma unroll
    for (int mt = 0; mt < 2; ++mt) {
      const int u0 = mt * 16 + kg * 4;
      if (u0 <= 24) {
        const f32x4 a = mt ? acc1[nt] : acc0[nt];
        uint2 pk;
        pk.x = (uint)f2bs(a[0]) | ((uint)f2bs(a[1]) << 16);
        pk.y = (uint)f2bs(a[2]) | ((uint)f2bs(a[3]) << 16);
        *(uint2*)&vs[t * 28 + u0] = pk;
      }
    }
  }
  __syncthreads();

  float s1 = 0.f, s2 = 0.f;
  ushort* yslab = yg + ((size_t)(n * 64 + o)) * 12800;
#pragma unroll
  for (int k = 0; k < 7; ++k) {
    const int grp = tid + k * 256;
    if (grp < 1600) {
      const int j0 = grp * 8;
      uint w[4];
#pragma unroll
      for (int e = 0; e < 4; ++e) {
        const int ja = j0 + e * 2, jb = ja + 1;
        const int ta = ja / 25, ua = ja - ta * 25;
        const int tb = jb / 25, ub = jb - tb * 25;
        const ushort wa = vs[ta * 28 + ua];
        const ushort wb = vs[tb * 28 + ub];
        w[e] = (uint)wa | ((uint)wb << 16);
        const float fa = bs2f(wa), fb = bs2f(wb);
        s1 += fa + fb; s2 += fa * fa + fb * fb;
      }
      int4 st; st.x = (int)w[0]; st.y = (int)w[1]; st.z = (int)w[2]; st.w = (int)w[3];
      *(int4*)&yslab[j0] = st;
    }
  }
  // stats reduce
#pragma unroll
  for (int off = 32; off > 0; off >>= 1) {
    s1 += __shfl_down(s1, off);
    s2 += __shfl_down(s2, off);
  }
  __shared__ float rs[8];
  if (lane == 0) { rs[wid] = s1; rs[4 + wid] = s2; }
  __syncthreads();
  if (tid == 0) {
    atomicAdd(&ssum[o], rs[0] + rs[1] + rs[2] + rs[3]);
    atomicAdd(&ssq[o], rs[4] + rs[5] + rs[6] + rs[7]);
  }
}

// ---------------------------------------------------------------------------
// K5: BN train-mode stats -> scale/shift
__global__ __launch_bounds__(64) void k_stats(const float* __restrict__ ssum,
    const float* __restrict__ ssq, const float* __restrict__ gamma,
    const float* __restrict__ beta, float* __restrict__ scl, float* __restrict__ shf) {
  const int o = threadIdx.x;
  const float inv = 1.0f / 409600.0f;          // N*T*V
  const float mu = ssum[o] * inv;
  const float var = ssq[o] * inv - mu * mu;    // biased
  const float rstd = rsqrtf(var + 1e-5f);
  const float sc = gamma[o] * rstd;
  scl[o] = sc;
  shf[o] = beta[o] - mu * sc;
}

// ---------------------------------------------------------------------------
// K6: out = relu(y) + y*scale[o] + shift[o] + x
__global__ __launch_bounds__(256) void k_final(const float* __restrict__ x,
    const ushort* __restrict__ yg, const float* __restrict__ scl,
    const float* __restrict__ shf, float* __restrict__ out) {
  const int stride = gridDim.x * blockDim.x;
  for (int i = blockIdx.x * 256 + threadIdx.x; i < 6553600; i += stride) {
    const int o = (i / 3200) & 63;             // 3200 float4 per (n,o) slab
    const float sc = scl[o], sh = shf[o];
    const float4 xv = ((const float4*)x)[i];
    const ushort4 yu = ((const ushort4*)yg)[i];
    const float y0 = bs2f(yu.x), y1 = bs2f(yu.y), y2 = bs2f(yu.z), y3 = bs2f(yu.w);
    float4 r;
    r.x = fmaxf(y0, 0.f) + y0 * sc + sh + xv.x;
    r.y = fmaxf(y1, 0.f) + y1 * sc + sh + xv.y;
    r.z = fmaxf(y2, 0.f) + y2 * sc + sh + xv.z;
    r.w = fmaxf(y3, 0.f) + y3 * sc + sh + xv.w;
    ((float4*)out)[i] = r;
  }
}

// ---------------------------------------------------------------------------
extern "C" void kernel_launch(void* const* d_in, const int* in_sizes, int n_in,
                              void* d_out, int out_size, void* d_ws, size_t ws_size,
                              hipStream_t stream) {
  const float* x     = (const float*)d_in[0];
  const float* A     = (const float*)d_in[1];
  const float* w1    = (const float*)d_in[2];
  const float* b1    = (const float*)d_in[3];
  const float* w2    = (const float*)d_in[4];
  const float* b2    = (const float*)d_in[5];
  const float* w3    = (const float*)d_in[6];
  const float* b3    = (const float*)d_in[7];
  const float* w4    = (const float*)d_in[8];
  const float* b4    = (const float*)d_in[9];
  const float* alpha = (const float*)d_in[10];
  const float* gamma = (const float*)d_in[11];
  const float* beta  = (const float*)d_in[12];
  float* ws = (float*)d_ws;
  float* attg = ws + ATT_OFF;
  ushort* yg = (ushort*)((char*)d_ws + Y_BYTE_OFF);
  ushort* vtb = (ushort*)((char*)d_ws + VT_BYTE_OFF);
  float* out = (float*)d_out;

  k_xm<<<2048, 256, 0, stream>>>(x, ws);
  k_att<<<768, 256, 0, stream>>>(ws, A, w1, b1, w2, b2, w4, b4, alpha, attg);
  for (int ph = 0; ph < 2; ++ph) {
    const int n_base = ph * 16;
    k_conv3<<<800, 256, 0, stream>>>(x, w3, b3, vtb, n_base);
    k_agg<<<1024, 256, 0, stream>>>(vtb, attg, ws + SSUM_OFF, ws + SSQ_OFF, yg, n_base);
  }
  k_stats<<<1, 64, 0, stream>>>(ws + SSUM_OFF, ws + SSQ_OFF, gamma, beta,
                                ws + SCL_OFF, ws + SHF_OFF);
  k_final<<<2048, 256, 0, stream>>>(x, yg, ws + SCL_OFF, ws + SHF_OFF, out);
}

// Round 4
// 414.846 us; speedup vs baseline: 2.3594x; 1.0112x over previous
//
#include <hip/hip_runtime.h>
#include <hip/hip_bf16.h>

// Problem constants: N=32, C_IN=C_OUT=64, T=512, V=25, S=3, R=32
// ws layout
#define XM_OFF   0             // 51200 f32
#define SSUM_OFF 51200         // 64
#define SSQ_OFF  51264         // 64
#define SCL_OFF  51328         // 64
#define SHF_OFF  51392         // 64
#define ATTF_BYTE_OFF (51456ull * 4ull)              // attf bf16 frag: 32*3*64*1024 u16 = 12.58 MB
#define Y_BYTE_OFF (ATTF_BYTE_OFF + 12582912ull)     // bf16 y: 26214400 elems = 52.4 MB

typedef __attribute__((ext_vector_type(8))) short short8;
typedef __attribute__((ext_vector_type(4))) float f32x4;

__device__ __forceinline__ ushort f2bs(float f) {
  __hip_bfloat16 h = __float2bfloat16(f);
  ushort u; __builtin_memcpy(&u, &h, 2); return u;
}
__device__ __forceinline__ float bs2f(ushort u) {
  return __uint_as_float((unsigned)u << 16);
}

// ---------------------------------------------------------------------------
// K1: xm[n,c,v] = mean_t x[n,c,t,v]; block per (n,c). Also zero BN stat accums.
__global__ __launch_bounds__(256) void k_xm(const float* __restrict__ x,
                                            float* __restrict__ ws) {
  const int b = blockIdx.x;            // n*64 + c
  const int tid = threadIdx.x;
  if (b == 0 && tid < 128) ws[SSUM_OFF + tid] = 0.f;   // zero ssum+ssq
  const float* base = x + (size_t)b * 12800;
  float acc[25];
#pragma unroll
  for (int v = 0; v < 25; ++v) acc[v] = 0.f;
  for (int t = tid; t < 512; t += 256) {
    const float* row = base + t * 25;
#pragma unroll
    for (int v = 0; v < 25; ++v) acc[v] += row[v];
  }
  __shared__ float red[256][25];
#pragma unroll
  for (int v = 0; v < 25; ++v) red[tid][v] = acc[v];
  __syncthreads();
  for (int st = 128; st > 0; st >>= 1) {
    if (tid < st) {
#pragma unroll
      for (int v = 0; v < 25; ++v) red[tid][v] += red[tid + st][v];
    }
    __syncthreads();
  }
  if (tid < 25) ws[XM_OFF + b * 25 + tid] = red[0][tid] * (1.0f / 512.0f);
}

// ---------------------------------------------------------------------------
// K2: att -> bf16 MFMA-A-fragment layout attf[(n*3+s)*64+o][mt(2)][lane(64)][8]
// att[n,s,o,u,v] = (sum_r w4[s,o,r]*relu(q[r,u]-k[r,v]) + b4[s,o])*alpha[s] + A[s,u,v]
__global__ __launch_bounds__(256) void k_att(const float* __restrict__ ws,
    const float* __restrict__ A, const float* __restrict__ w1, const float* __restrict__ b1,
    const float* __restrict__ w2, const float* __restrict__ b2, const float* __restrict__ w4,
    const float* __restrict__ b4, const float* __restrict__ alpha, uint* __restrict__ attf) {
  const int b = blockIdx.x;
  const int n = b / 24; const int r = b % 24; const int s = r >> 3; const int og = r & 7;
  const int tid = threadIdx.x;
  __shared__ float xs[1600];   // xm[n][c][v]
  __shared__ float qb[800];    // q[r][v]
  __shared__ float kb[800];    // k[r][v]
  __shared__ float att8[8][625];
  for (int j = tid; j < 1600; j += 256) xs[j] = ws[XM_OFF + n * 1600 + j];
  __syncthreads();
  for (int i = tid; i < 1600; i += 256) {
    const int half = i / 800;
    const int ii = i % 800;
    const int rr = ii / 25, v = ii % 25;
    const float* w = half ? w2 : w1;
    const float* bb = half ? b2 : b1;
    float acc = bb[s * 32 + rr];
    const float* wr = w + (s * 32 + rr) * 64;
#pragma unroll 8
    for (int c = 0; c < 64; ++c) acc += wr[c] * xs[c * 25 + v];
    (half ? kb : qb)[ii] = acc;
  }
  __syncthreads();
  const float al = alpha[s];
  for (int i = tid; i < 5000; i += 256) {
    const int o2 = i / 625, r2 = i % 625;
    const int u = r2 / 25, v = r2 % 25;
    const int o = og * 8 + o2;
    const float* wr = w4 + (s * 64 + o) * 32;
    float acc = 0.f;
#pragma unroll 8
    for (int rr2 = 0; rr2 < 32; ++rr2) {
      const float d = qb[rr2 * 25 + u] - kb[rr2 * 25 + v];
      acc += wr[rr2] * fmaxf(d, 0.f);
    }
    att8[o2][r2] = (acc + b4[s * 64 + o]) * al + A[s * 625 + r2];
  }
  __syncthreads();
  // emit frag layout: per o, 512 u32 words: word = mt*256 + lane*4 + pr
  for (int w = tid; w < 4096; w += 256) {
    const int o2 = w >> 9, widx = w & 511;
    const int mt = widx >> 8, lane = (widx >> 2) & 63, pr = widx & 3;
    const int kg = lane >> 4, colu = lane & 15;
    const int u = mt * 16 + colu;
    const int i0 = pr * 2;
    const int v0 = kg * 4 + (i0 & 3) + ((i0 >> 2) << 4);
    const float f0 = (u < 25 && v0 < 25) ? att8[o2][u * 25 + v0] : 0.f;
    const float f1 = (u < 25 && (v0 + 1) < 25) ? att8[o2][u * 25 + v0 + 1] : 0.f;
    attf[((size_t)(n * 3 + s) * 64 + og * 8 + o2) * 512 + widx] =
        (uint)f2bs(f0) | ((uint)f2bs(f1) << 16);
  }
}

// ---------------------------------------------------------------------------
// K3: fused conv3 + aggregation. Block=(n, t-chunk of 16), 512 thr = 8 waves.
// per s: conv3 MFMAs -> vt_s LDS; agg MFMAs accumulate y in regs. No vt in HBM.
__global__ __launch_bounds__(512, 2) void k_fused(const float* __restrict__ x,
    const float* __restrict__ w3, const float* __restrict__ b3,
    const ushort* __restrict__ attf, float* __restrict__ ssum, float* __restrict__ ssq,
    ushort* __restrict__ yg) {
  __shared__ ushort xl[64 * 404];      // x bf16 [c][item], stride 404 (bank spread)
  __shared__ ushort vs[64 * 400];      // vt_s [o][item] / later y-pack [o][t*25+u]
  __shared__ float sS[64], sQ[64];
  const int bid = blockIdx.x;
  // XCD-aware swizzle: same n -> same XCD (8 XCDs, 1024 blocks = 8*128)
  const int xcd = bid & 7, jj = bid >> 3;
  const int n = xcd + ((jj >> 5) << 3);
  const int tc = jj & 31;
  const int t0 = tc << 4;
  const int tid = threadIdx.x;
  const int lane = tid & 63, wid = tid >> 6;
  const int kg = lane >> 4, col = lane & 15;

  // ---- stage x slab [64c][400 items] -> bf16 LDS
  {
    const float* xb = x + (size_t)n * 819200 + t0 * 25;
    for (int i = tid; i < 6400; i += 512) {
      const int c = i / 100, r = i - c * 100;
      const float4 f = *(const float4*)(xb + (size_t)c * 12800 + (r << 2));
      ushort4 p; p.x = f2bs(f.x); p.y = f2bs(f.y); p.z = f2bs(f.z); p.w = f2bs(f.w);
      *(ushort4*)&xl[c * 404 + (r << 2)] = p;
    }
  }

  f32x4 yacc[8][2];
#pragma unroll
  for (int oi = 0; oi < 8; ++oi) { yacc[oi][0] = (f32x4)0.f; yacc[oi][1] = (f32x4)0.f; }

  __syncthreads();

  const int od = wid << 3;             // this wave's 8 o's for agg

  for (int s = 0; s < 3; ++s) {
    // ---- A-frags (w3[s]) + bias: row o = mt*16+col, k = kb*32 + kg*4+(i&3)+16*(i>>2)
    short8 af[4][2];
    float4 b3f[4];
#pragma unroll
    for (int mt = 0; mt < 4; ++mt) {
      const float* wrow = w3 + ((size_t)s * 64 + mt * 16 + col) * 64;
#pragma unroll
      for (int kb = 0; kb < 2; ++kb) {
        const float4 lo = *(const float4*)(wrow + kb * 32 + kg * 4);
        const float4 hi = *(const float4*)(wrow + kb * 32 + 16 + kg * 4);
        short8 a;
        a[0] = (short)f2bs(lo.x); a[1] = (short)f2bs(lo.y);
        a[2] = (short)f2bs(lo.z); a[3] = (short)f2bs(lo.w);
        a[4] = (short)f2bs(hi.x); a[5] = (short)f2bs(hi.y);
        a[6] = (short)f2bs(hi.z); a[7] = (short)f2bs(hi.w);
        af[mt][kb] = a;
      }
      b3f[mt] = *(const float4*)(b3 + s * 64 + mt * 16 + kg * 4);
    }

    // ---- conv3: wave handles nt = wid, wid+8, wid+16(, 24)
    for (int nt = wid; nt < 25; nt += 8) {
      const int item = nt * 16 + col;
      short8 b0, b1;
#pragma unroll
      for (int i = 0; i < 8; ++i) {
        const int c0 = kg * 4 + (i & 3) + ((i >> 2) << 4);
        b0[i] = (short)xl[c0 * 404 + item];
        b1[i] = (short)xl[(c0 + 32) * 404 + item];
      }
#pragma unroll
      for (int mt = 0; mt < 4; ++mt) {
        f32x4 acc;
        acc[0] = b3f[mt].x; acc[1] = b3f[mt].y; acc[2] = b3f[mt].z; acc[3] = b3f[mt].w;
        acc = __builtin_amdgcn_mfma_f32_16x16x32_bf16(af[mt][0], b0, acc, 0, 0, 0);
        acc = __builtin_amdgcn_mfma_f32_16x16x32_bf16(af[mt][1], b1, acc, 0, 0, 0);
#pragma unroll
        for (int r = 0; r < 4; ++r)
          vs[(mt * 16 + kg * 4 + r) * 400 + item] = f2bs(acc[r]);
      }
    }
    __syncthreads();

    // ---- agg: wave owns o = od..od+7. A = attf (b128 x2), B from vt_s.
    const ushort* apbase = attf + (((size_t)(n * 3 + s) * 64 + od) << 10);
#pragma unroll
    for (int oi = 0; oi < 8; ++oi) {
      const ushort* ap = apbase + ((size_t)oi << 10);
      const short8 A0 = *(const short8*)(ap + lane * 8);
      const short8 A1 = *(const short8*)(ap + 512 + lane * 8);
      short8 bfr;
#pragma unroll
      for (int i = 0; i < 8; ++i) {
        const int v = kg * 4 + (i & 3) + ((i >> 2) << 4);
        bfr[i] = (v < 25) ? (short)vs[(od + oi) * 400 + col * 25 + v] : (short)0;
      }
      yacc[oi][0] = __builtin_amdgcn_mfma_f32_16x16x32_bf16(A0, bfr, yacc[oi][0], 0, 0, 0);
      yacc[oi][1] = __builtin_amdgcn_mfma_f32_16x16x32_bf16(A1, bfr, yacc[oi][1], 0, 0, 0);
    }
    __syncthreads();   // vt_s free for next s
  }

  // ---- BN partial stats: each (wave, oi) owns one o entirely
#pragma unroll
  for (int oi = 0; oi < 8; ++oi) {
    float a1 = 0.f, a2 = 0.f;
#pragma unroll
    for (int mt = 0; mt < 2; ++mt) {
#pragma unroll
      for (int r = 0; r < 4; ++r) {
        const int u = mt * 16 + kg * 4 + r;
        if (u < 25) {
          const float v = yacc[oi][mt][r];
          a1 += v; a2 += v * v;
        }
      }
    }
#pragma unroll
    for (int off = 32; off > 0; off >>= 1) {
      a1 += __shfl_down(a1, off);
      a2 += __shfl_down(a2, off);
    }
    if (lane == 0) { sS[od + oi] = a1; sQ[od + oi] = a2; }
  }

  // ---- pack y into vs as [o][t*25+u] (linear y-chunk), then coalesced stores
#pragma unroll
  for (int oi = 0; oi < 8; ++oi) {
#pragma unroll
    for (int mt = 0; mt < 2; ++mt) {
      const int u0 = mt * 16 + kg * 4;
#pragma unroll
      for (int r = 0; r < 4; ++r) {
        const int u = u0 + r;
        if (u < 25) vs[(od + oi) * 400 + col * 25 + u] = f2bs(yacc[oi][mt][r]);
      }
    }
  }
  __syncthreads();

  {
    const size_t ybase = ((size_t)n * 64) * 12800 + (size_t)t0 * 25;
    for (int k2 = tid; k2 < 3200; k2 += 512) {
      const int o = k2 / 50, rem = k2 - o * 50;
      const int4 w = *(const int4*)&vs[o * 400 + rem * 8];
      *(int4*)(yg + ybase + (size_t)o * 12800 + rem * 8) = w;
    }
  }
  if (tid < 64) {
    atomicAdd(&ssum[tid], sS[tid]);
    atomicAdd(&ssq[tid], sQ[tid]);
  }
}

// ---------------------------------------------------------------------------
// K4: BN train-mode stats -> scale/shift
__global__ __launch_bounds__(64) void k_stats(const float* __restrict__ ssum,
    const float* __restrict__ ssq, const float* __restrict__ gamma,
    const float* __restrict__ beta, float* __restrict__ scl, float* __restrict__ shf) {
  const int o = threadIdx.x;
  const float inv = 1.0f / 409600.0f;          // N*T*V
  const float mu = ssum[o] * inv;
  const float var = ssq[o] * inv - mu * mu;    // biased
  const float rstd = rsqrtf(var + 1e-5f);
  const float sc = gamma[o] * rstd;
  scl[o] = sc;
  shf[o] = beta[o] - mu * sc;
}

// ---------------------------------------------------------------------------
// K5: out = relu(y) + y*scale[o] + shift[o] + x
__global__ __launch_bounds__(256) void k_final(const float* __restrict__ x,
    const ushort* __restrict__ yg, const float* __restrict__ scl,
    const float* __restrict__ shf, float* __restrict__ out) {
  const int stride = gridDim.x * blockDim.x;
  for (int i = blockIdx.x * 256 + threadIdx.x; i < 6553600; i += stride) {
    const int o = (i / 3200) & 63;             // 3200 float4 per (n,o) slab
    const float sc = scl[o], sh = shf[o];
    const float4 xv = ((const float4*)x)[i];
    const ushort4 yu = ((const ushort4*)yg)[i];
    const float y0 = bs2f(yu.x), y1 = bs2f(yu.y), y2 = bs2f(yu.z), y3 = bs2f(yu.w);
    float4 r;
    r.x = fmaxf(y0, 0.f) + y0 * sc + sh + xv.x;
    r.y = fmaxf(y1, 0.f) + y1 * sc + sh + xv.y;
    r.z = fmaxf(y2, 0.f) + y2 * sc + sh + xv.z;
    r.w = fmaxf(y3, 0.f) + y3 * sc + sh + xv.w;
    ((float4*)out)[i] = r;
  }
}

// ---------------------------------------------------------------------------
extern "C" void kernel_launch(void* const* d_in, const int* in_sizes, int n_in,
                              void* d_out, int out_size, void* d_ws, size_t ws_size,
                              hipStream_t stream) {
  const float* x     = (const float*)d_in[0];
  const float* A     = (const float*)d_in[1];
  const float* w1    = (const float*)d_in[2];
  const float* b1    = (const float*)d_in[3];
  const float* w2    = (const float*)d_in[4];
  const float* b2    = (const float*)d_in[5];
  const float* w3    = (const float*)d_in[6];
  const float* b3    = (const float*)d_in[7];
  const float* w4    = (const float*)d_in[8];
  const float* b4    = (const float*)d_in[9];
  const float* alpha = (const float*)d_in[10];
  const float* gamma = (const float*)d_in[11];
  const float* beta  = (const float*)d_in[12];
  float* ws = (float*)d_ws;
  uint* attf_w = (uint*)((char*)d_ws + ATTF_BYTE_OFF);
  const ushort* attf_r = (const ushort*)((char*)d_ws + ATTF_BYTE_OFF);
  ushort* yg = (ushort*)((char*)d_ws + Y_BYTE_OFF);
  float* out = (float*)d_out;

  k_xm<<<2048, 256, 0, stream>>>(x, ws);
  k_att<<<768, 256, 0, stream>>>(ws, A, w1, b1, w2, b2, w4, b4, alpha, attf_w);
  k_fused<<<1024, 512, 0, stream>>>(x, w3, b3, attf_r, ws + SSUM_OFF, ws + SSQ_OFF, yg);
  k_stats<<<1, 64, 0, stream>>>(ws + SSUM_OFF, ws + SSQ_OFF, gamma, beta,
                                ws + SCL_OFF, ws + SHF_OFF);
  k_final<<<2048, 256, 0, stream>>>(x, yg, ws + SCL_OFF, ws + SHF_OFF, out);
}